// Round 1
// baseline (2150.100 us; speedup 1.0000x reference)
//
#include <hip/hip_runtime.h>
#include <cstdint>
#include <cstddef>

#define KKSLOTS 25

// ---------------------------------------------------------------------------
// degree count (incoming edges per node)
// ---------------------------------------------------------------------------
__global__ void deg_count_kernel(const int* __restrict__ dst, float* __restrict__ deg, int E) {
    int e = blockIdx.x * blockDim.x + threadIdx.x;
    if (e < E) atomicAdd(&deg[dst[e]], 1.0f);
}

// ---------------------------------------------------------------------------
// scatter edge messages in INPUT space: acc[dst, k, i] += w_c * x[src, i]
// one thread per (edge, i); 4 spline corners per thread.
// ---------------------------------------------------------------------------
template<int I>
__global__ void scatter_kernel(const float* __restrict__ x,
                               const int* __restrict__ src,
                               const int* __restrict__ dst,
                               const float* __restrict__ pseudo,
                               float* __restrict__ acc,
                               int E, int nlo, int nhi) {
    long long tid = (long long)blockIdx.x * blockDim.x + threadIdx.x;
    int e = (int)(tid / I);
    int i = (int)(tid % I);
    if (e >= E) return;
    int d = dst[e];
    if (d < nlo || d >= nhi) return;
    int s = src[e];
    float xv = x[(size_t)s * I + i];
    float v0 = pseudo[2 * e + 0] * 4.0f;   // (K-1) = 4
    float v1 = pseudo[2 * e + 1] * 4.0f;
    float fl0 = floorf(v0), fl1 = floorf(v1);
    float f0 = v0 - fl0, f1 = v1 - fl1;
    int b0 = (int)fl0, b1 = (int)fl1;
    float* base = acc + (size_t)(d - nlo) * (KKSLOTS * I) + i;
    #pragma unroll
    for (int s0 = 0; s0 < 2; ++s0) {
        float w0 = s0 ? f0 : (1.0f - f0);
        int i0 = min(max(b0 + s0, 0), 4);
        #pragma unroll
        for (int s1 = 0; s1 < 2; ++s1) {
            float w1 = s1 ? f1 : (1.0f - f1);
            int i1 = min(max(b1 + s1, 0), 4);
            atomicAdd(base + (size_t)(i0 * 5 + i1) * I, w0 * w1 * xv);
        }
    }
}

// ---------------------------------------------------------------------------
// dense contraction: hout[n,o] = elu( (sum_{k,i} acc[n,k,i]*W[k,i,o]) / deg
//                                     + sum_i hin[n,i]*root[i,o] + bias[o] )
// LDS-tiled GEMM: TN=64 nodes per block, K-chunks of 64.
// thread layout: 256 threads = NG groups x OL o-lanes;
// each thread owns NPT node-rows and OPT o-columns.
// ---------------------------------------------------------------------------
template<int I, int O, int OL>
__global__ __launch_bounds__(256) void contract_kernel(
        const float* __restrict__ acc, const float* __restrict__ hin,
        const float* __restrict__ W, const float* __restrict__ root,
        const float* __restrict__ bias, const float* __restrict__ deg,
        float* __restrict__ hout, int nlo, int nhi) {
    constexpr int K   = KKSLOTS * I;
    constexpr int KCH = 64;
    constexpr int TN  = 64;
    constexpr int NG  = 256 / OL;
    constexpr int NPT = TN / NG;
    constexpr int OPT = (O + OL - 1) / OL;
    __shared__ float a_tile[TN][KCH];
    __shared__ float w_tile[KCH][O];
    int tid = threadIdx.x;
    int n0 = nlo + blockIdx.x * TN;
    int lane_o = tid % OL;
    int grp = tid / OL;
    float c[NPT][OPT];
    #pragma unroll
    for (int j = 0; j < NPT; ++j)
        #pragma unroll
        for (int pq = 0; pq < OPT; ++pq) c[j][pq] = 0.0f;

    for (int k0 = 0; k0 < K; k0 += KCH) {
        // stage acc tile (coalesced: 64 consecutive k per row)
        int kk = tid & 63;
        int rbase = (tid >> 6) * (TN / 4);
        #pragma unroll
        for (int j = 0; j < TN / 4; ++j) {
            int nn = rbase + j;
            int n = n0 + nn;
            int gk = k0 + kk;
            float v = 0.0f;
            if (n < nhi && gk < K) v = acc[(size_t)(n - nlo) * K + gk];
            a_tile[nn][kk] = v;
        }
        // stage W tile
        for (int t = tid; t < KCH * O; t += 256) {
            int kq = t / O, oq = t - kq * O;
            int gk = k0 + kq;
            w_tile[kq][oq] = (gk < K) ? W[(size_t)gk * O + oq] : 0.0f;
        }
        __syncthreads();
        #pragma unroll 8
        for (int kk2 = 0; kk2 < KCH; ++kk2) {
            float wv[OPT];
            #pragma unroll
            for (int pq = 0; pq < OPT; ++pq) {
                int oo = lane_o + pq * OL;
                wv[pq] = (oo < O) ? w_tile[kk2][oo] : 0.0f;
            }
            #pragma unroll
            for (int j = 0; j < NPT; ++j) {
                float a = a_tile[grp * NPT + j][kk2];
                #pragma unroll
                for (int pq = 0; pq < OPT; ++pq) c[j][pq] = fmaf(a, wv[pq], c[j][pq]);
            }
        }
        __syncthreads();
    }

    // epilogue: deg mean, root term, bias, ELU
    #pragma unroll
    for (int j = 0; j < NPT; ++j) {
        int n = n0 + grp * NPT + j;
        if (n >= nhi) continue;
        float dinv = 1.0f / fmaxf(deg[n], 1.0f);
        #pragma unroll
        for (int pq = 0; pq < OPT; ++pq) {
            int oo = lane_o + pq * OL;
            if (oo >= O) continue;
            float r = 0.0f;
            for (int i = 0; i < I; ++i)
                r = fmaf(hin[(size_t)n * I + i], root[(size_t)i * O + oo], r);
            float v = fmaf(c[j][pq], dinv, r + bias[oo]);
            hout[(size_t)n * O + oo] = (v > 0.0f) ? v : expm1f(v);
        }
    }
}

// ---------------------------------------------------------------------------
// graph mean: atomic sums into g[64,124] and counts
// ---------------------------------------------------------------------------
__global__ void graph_sum_kernel(const float* __restrict__ h3, const int* __restrict__ batch,
                                 float* __restrict__ g, float* __restrict__ cnt, int N) {
    int tid = blockIdx.x * blockDim.x + threadIdx.x;
    int n = tid / 124;
    int o = tid - n * 124;
    if (n >= N) return;
    int b = batch[n];
    atomicAdd(&g[b * 124 + o], h3[(size_t)n * 124 + o]);
    if (o == 0) atomicAdd(&cnt[b], 1.0f);
}

// ---------------------------------------------------------------------------
// head: logits = (g/cnt) @ fc_w + fc_b ; log_softmax
// ---------------------------------------------------------------------------
__global__ void head_kernel(const float* __restrict__ g, const float* __restrict__ cnt,
                            const float* __restrict__ fcw, const float* __restrict__ fcb,
                            float* __restrict__ out) {
    __shared__ float logits[32];
    __shared__ float red[2];
    int b = blockIdx.x;
    int o = threadIdx.x;
    float c = fmaxf(cnt[b], 1.0f);
    if (o < 30) {
        float a = fcb[o];
        for (int i = 0; i < 124; ++i)
            a = fmaf(g[b * 124 + i] / c, fcw[i * 30 + o], a);
        logits[o] = a;
    }
    __syncthreads();
    if (o == 0) {
        float m = -1e30f;
        for (int j = 0; j < 30; ++j) m = fmaxf(m, logits[j]);
        float s = 0.0f;
        for (int j = 0; j < 30; ++j) s += expf(logits[j] - m);
        red[0] = m;
        red[1] = logf(s);
    }
    __syncthreads();
    if (o < 30) out[b * 30 + o] = logits[o] - red[0] - red[1];
}

// ---------------------------------------------------------------------------
// per-layer driver (node-chunked so acc fits whatever ws_size allows)
// ---------------------------------------------------------------------------
template<int I, int O, int OL>
static void run_layer(const float* hin, const float* W, const float* root, const float* bias,
                      float* hout, float* acc, const float* deg,
                      const int* srcp, const int* dstp, const float* pseudo,
                      int N, int E, size_t avail, hipStream_t stream) {
    size_t perNode = (size_t)KKSLOTS * I * 4;
    size_t maxNodesS = avail / perNode;
    int maxNodes = (maxNodesS > (size_t)N) ? N : (int)maxNodesS;
    if (maxNodes < 1) maxNodes = 1;
    for (int nlo = 0; nlo < N; nlo += maxNodes) {
        int nhi = nlo + maxNodes;
        if (nhi > N) nhi = N;
        hipMemsetAsync(acc, 0, (size_t)(nhi - nlo) * perNode, stream);
        long long threads = (long long)E * I;
        int blocks = (int)((threads + 255) / 256);
        scatter_kernel<I><<<blocks, 256, 0, stream>>>(hin, srcp, dstp, pseudo, acc, E, nlo, nhi);
        int nb = (nhi - nlo + 63) / 64;
        contract_kernel<I, O, OL><<<nb, 256, 0, stream>>>(acc, hin, W, root, bias, deg, hout, nlo, nhi);
    }
}

extern "C" void kernel_launch(void* const* d_in, const int* in_sizes, int n_in,
                              void* d_out, int out_size, void* d_ws, size_t ws_size,
                              hipStream_t stream) {
    const float* x      = (const float*)d_in[0];
    const int*   ei     = (const int*)  d_in[1];
    const float* pseudo = (const float*)d_in[2];
    const int*   batch  = (const int*)  d_in[3];
    const float* W1 = (const float*)d_in[4];
    const float* r1 = (const float*)d_in[5];
    const float* b1 = (const float*)d_in[6];
    const float* W2 = (const float*)d_in[7];
    const float* r2 = (const float*)d_in[8];
    const float* b2 = (const float*)d_in[9];
    const float* W3 = (const float*)d_in[10];
    const float* r3 = (const float*)d_in[11];
    const float* b3 = (const float*)d_in[12];
    const float* fcw = (const float*)d_in[13];
    const float* fcb = (const float*)d_in[14];

    int N = in_sizes[0] / 8;
    int E = in_sizes[1] / 2;
    const int* srcp = ei;
    const int* dstp = ei + E;

    // workspace carve
    char* p = (char*)d_ws;
    float* h1   = (float*)p; p += (size_t)N * 32 * 4;
    float* h2   = (float*)p; p += (size_t)N * 64 * 4;
    float* h3   = (float*)p; p += (size_t)N * 124 * 4;
    float* deg  = (float*)p; p += (size_t)N * 4;
    float* gbuf = (float*)p; p += 64 * 124 * 4;
    float* cnt  = (float*)p; p += 256;
    float* acc  = (float*)p;
    size_t used = (size_t)(p - (char*)d_ws);
    size_t avail = (ws_size > used) ? (ws_size - used) : 0;

    // zero deg + g + cnt in one shot (contiguous)
    hipMemsetAsync(deg, 0, (size_t)N * 4 + 64 * 124 * 4 + 256, stream);
    deg_count_kernel<<<(E + 255) / 256, 256, 0, stream>>>(dstp, deg, E);

    run_layer<8, 32, 32>(x,  W1, r1, b1, h1, acc, deg, srcp, dstp, pseudo, N, E, avail, stream);
    run_layer<32, 64, 64>(h1, W2, r2, b2, h2, acc, deg, srcp, dstp, pseudo, N, E, avail, stream);
    run_layer<64, 124, 64>(h2, W3, r3, b3, h3, acc, deg, srcp, dstp, pseudo, N, E, avail, stream);

    int tot = N * 124;
    graph_sum_kernel<<<(tot + 255) / 256, 256, 0, stream>>>(h3, batch, gbuf, cnt, N);
    head_kernel<<<64, 64, 0, stream>>>(gbuf, cnt, fcw, fcb, (float*)d_out);
}

// Round 2
// 1799.058 us; speedup vs baseline: 1.1951x; 1.1951x over previous
//
#include <hip/hip_runtime.h>
#include <cstdint>
#include <cstddef>

#define KKSLOTS 25

// ---------------------------------------------------------------------------
// degree count (incoming edges per node)
// ---------------------------------------------------------------------------
__global__ void deg_count_kernel(const int* __restrict__ dst, float* __restrict__ deg, int E) {
    int e = blockIdx.x * blockDim.x + threadIdx.x;
    if (e < E) atomicAdd(&deg[dst[e]], 1.0f);
}

// ---------------------------------------------------------------------------
// scatter edge messages in INPUT space: acc[dst, k, i] += w_c * x[src, i]
// one thread per (edge, i); 4 spline corners per thread.
// ---------------------------------------------------------------------------
template<int I>
__global__ void scatter_kernel(const float* __restrict__ x,
                               const int* __restrict__ src,
                               const int* __restrict__ dst,
                               const float* __restrict__ pseudo,
                               float* __restrict__ acc,
                               int E, int nlo, int nhi) {
    long long tid = (long long)blockIdx.x * blockDim.x + threadIdx.x;
    int e = (int)(tid / I);
    int i = (int)(tid % I);
    if (e >= E) return;
    int d = dst[e];
    if (d < nlo || d >= nhi) return;
    int s = src[e];
    float xv = x[(size_t)s * I + i];
    float v0 = pseudo[2 * e + 0] * 4.0f;   // (K-1) = 4
    float v1 = pseudo[2 * e + 1] * 4.0f;
    float fl0 = floorf(v0), fl1 = floorf(v1);
    float f0 = v0 - fl0, f1 = v1 - fl1;
    int b0 = (int)fl0, b1 = (int)fl1;
    float* base = acc + (size_t)(d - nlo) * (KKSLOTS * I) + i;
    #pragma unroll
    for (int s0 = 0; s0 < 2; ++s0) {
        float w0 = s0 ? f0 : (1.0f - f0);
        int i0 = min(max(b0 + s0, 0), 4);
        #pragma unroll
        for (int s1 = 0; s1 < 2; ++s1) {
            float w1 = s1 ? f1 : (1.0f - f1);
            int i1 = min(max(b1 + s1, 0), 4);
            atomicAdd(base + (size_t)(i0 * 5 + i1) * I, w0 * w1 * xv);
        }
    }
}

// ---------------------------------------------------------------------------
// dense contraction, register-blocked GEMM:
// hout[n,o] = elu( (sum_k acc[n,k]*W[k,o]) / deg[n] + sum_i hin[n,i]*root[i,o] + bias[o] )
// Block: TN=64 nodes x TO outputs. 256 threads, thread tile NPT nodes x 4 outputs.
// k-step of 4 with float4 LDS reads on both operands -> VALU-bound inner loop.
// ---------------------------------------------------------------------------
template<int I, int O, int TO>
__global__ __launch_bounds__(256) void contract_kernel(
        const float* __restrict__ acc, const float* __restrict__ hin,
        const float* __restrict__ W, const float* __restrict__ root,
        const float* __restrict__ bias, const float* __restrict__ deg,
        float* __restrict__ hout, int nlo, int nhi) {
    constexpr int K   = KKSLOTS * I;
    constexpr int KCH = 64;
    constexpr int TN  = 64;
    constexpr int OG  = TO / 4;        // threads along o
    constexpr int NG  = 256 / OG;      // threads along n
    constexpr int NPT = TN / NG;       // node rows per thread
    __shared__ float a_tile[TN][KCH + 4];   // +4: float4-aligned rows, conflict-free staging
    __shared__ float w_tile[KCH][TO];

    int tid = threadIdx.x;
    int n0 = nlo + blockIdx.x * TN;
    int otile = blockIdx.y * TO;
    int og = tid % OG;
    int ng = tid / OG;
    int obase = otile + og * 4;

    float c[NPT][4];
    #pragma unroll
    for (int j = 0; j < NPT; ++j)
        #pragma unroll
        for (int p = 0; p < 4; ++p) c[j][p] = 0.0f;

    for (int k0 = 0; k0 < K; k0 += KCH) {
        // stage acc tile: lane = kk (coalesced along k), rows of 4 per pass
        int kk = tid & 63;
        int rbase = (tid >> 6) * (TN / 4);
        int gk = k0 + kk;
        #pragma unroll
        for (int j2 = 0; j2 < TN / 4; ++j2) {
            int nn = rbase + j2;
            int n = n0 + nn;
            float v = 0.0f;
            if (n < nhi && gk < K) v = acc[(size_t)(n - nlo) * K + gk];
            a_tile[nn][kk] = v;
        }
        // stage W tile (coalesced along o)
        for (int t = tid; t < KCH * TO; t += 256) {
            int kq = t / TO, oq = t - kq * TO;
            int gkw = k0 + kq;
            int oo = otile + oq;
            w_tile[kq][oq] = (gkw < K && oo < O) ? W[(size_t)gkw * O + oo] : 0.0f;
        }
        __syncthreads();
        #pragma unroll 4
        for (int kk2 = 0; kk2 < KCH; kk2 += 4) {
            float4 wv0 = *(const float4*)&w_tile[kk2 + 0][og * 4];
            float4 wv1 = *(const float4*)&w_tile[kk2 + 1][og * 4];
            float4 wv2 = *(const float4*)&w_tile[kk2 + 2][og * 4];
            float4 wv3 = *(const float4*)&w_tile[kk2 + 3][og * 4];
            #pragma unroll
            for (int j = 0; j < NPT; ++j) {
                float4 av = *(const float4*)&a_tile[ng * NPT + j][kk2];
                c[j][0] = fmaf(av.x, wv0.x, c[j][0]); c[j][1] = fmaf(av.x, wv0.y, c[j][1]);
                c[j][2] = fmaf(av.x, wv0.z, c[j][2]); c[j][3] = fmaf(av.x, wv0.w, c[j][3]);
                c[j][0] = fmaf(av.y, wv1.x, c[j][0]); c[j][1] = fmaf(av.y, wv1.y, c[j][1]);
                c[j][2] = fmaf(av.y, wv1.z, c[j][2]); c[j][3] = fmaf(av.y, wv1.w, c[j][3]);
                c[j][0] = fmaf(av.z, wv2.x, c[j][0]); c[j][1] = fmaf(av.z, wv2.y, c[j][1]);
                c[j][2] = fmaf(av.z, wv2.z, c[j][2]); c[j][3] = fmaf(av.z, wv2.w, c[j][3]);
                c[j][0] = fmaf(av.w, wv3.x, c[j][0]); c[j][1] = fmaf(av.w, wv3.y, c[j][1]);
                c[j][2] = fmaf(av.w, wv3.z, c[j][2]); c[j][3] = fmaf(av.w, wv3.w, c[j][3]);
            }
        }
        __syncthreads();
    }

    // epilogue: deg mean, root term, bias, ELU
    if (obase >= O) return;
    bool full4 = (obase + 3 < O);
    #pragma unroll
    for (int j = 0; j < NPT; ++j) {
        int n = n0 + ng * NPT + j;
        if (n >= nhi) continue;
        float dinv = 1.0f / fmaxf(deg[n], 1.0f);
        float r[4] = {0.0f, 0.0f, 0.0f, 0.0f};
        if (full4) {
            for (int i = 0; i < I; ++i) {
                float hv = hin[(size_t)n * I + i];
                float4 rt = *(const float4*)&root[(size_t)i * O + obase];
                r[0] = fmaf(hv, rt.x, r[0]); r[1] = fmaf(hv, rt.y, r[1]);
                r[2] = fmaf(hv, rt.z, r[2]); r[3] = fmaf(hv, rt.w, r[3]);
            }
        } else {
            for (int i = 0; i < I; ++i) {
                float hv = hin[(size_t)n * I + i];
                #pragma unroll
                for (int p = 0; p < 4; ++p)
                    if (obase + p < O) r[p] = fmaf(hv, root[(size_t)i * O + obase + p], r[p]);
            }
        }
        #pragma unroll
        for (int p = 0; p < 4; ++p) {
            int oo = obase + p;
            if (oo >= O) continue;
            float v = fmaf(c[j][p], dinv, r[p] + bias[oo]);
            hout[(size_t)n * O + oo] = (v > 0.0f) ? v : expm1f(v);
        }
    }
}

// ---------------------------------------------------------------------------
// graph mean: atomic sums into g[64,124] and counts
// ---------------------------------------------------------------------------
__global__ void graph_sum_kernel(const float* __restrict__ h3, const int* __restrict__ batch,
                                 float* __restrict__ g, float* __restrict__ cnt, int N) {
    int tid = blockIdx.x * blockDim.x + threadIdx.x;
    int n = tid / 124;
    int o = tid - n * 124;
    if (n >= N) return;
    int b = batch[n];
    atomicAdd(&g[b * 124 + o], h3[(size_t)n * 124 + o]);
    if (o == 0) atomicAdd(&cnt[b], 1.0f);
}

// ---------------------------------------------------------------------------
// head: logits = (g/cnt) @ fc_w + fc_b ; log_softmax
// ---------------------------------------------------------------------------
__global__ void head_kernel(const float* __restrict__ g, const float* __restrict__ cnt,
                            const float* __restrict__ fcw, const float* __restrict__ fcb,
                            float* __restrict__ out) {
    __shared__ float logits[32];
    __shared__ float red[2];
    int b = blockIdx.x;
    int o = threadIdx.x;
    float c = fmaxf(cnt[b], 1.0f);
    if (o < 30) {
        float a = fcb[o];
        for (int i = 0; i < 124; ++i)
            a = fmaf(g[b * 124 + i] / c, fcw[i * 30 + o], a);
        logits[o] = a;
    }
    __syncthreads();
    if (o == 0) {
        float m = -1e30f;
        for (int j = 0; j < 30; ++j) m = fmaxf(m, logits[j]);
        float s = 0.0f;
        for (int j = 0; j < 30; ++j) s += expf(logits[j] - m);
        red[0] = m;
        red[1] = logf(s);
    }
    __syncthreads();
    if (o < 30) out[b * 30 + o] = logits[o] - red[0] - red[1];
}

// ---------------------------------------------------------------------------
// per-layer driver (node-chunked so acc fits whatever ws_size allows)
// ---------------------------------------------------------------------------
template<int I, int O, int TO>
static void run_layer(const float* hin, const float* W, const float* root, const float* bias,
                      float* hout, float* acc, const float* deg,
                      const int* srcp, const int* dstp, const float* pseudo,
                      int N, int E, size_t avail, hipStream_t stream) {
    size_t perNode = (size_t)KKSLOTS * I * 4;
    size_t maxNodesS = avail / perNode;
    int maxNodes = (maxNodesS > (size_t)N) ? N : (int)maxNodesS;
    if (maxNodes < 1) maxNodes = 1;
    for (int nlo = 0; nlo < N; nlo += maxNodes) {
        int nhi = nlo + maxNodes;
        if (nhi > N) nhi = N;
        hipMemsetAsync(acc, 0, (size_t)(nhi - nlo) * perNode, stream);
        long long threads = (long long)E * I;
        int blocks = (int)((threads + 255) / 256);
        scatter_kernel<I><<<blocks, 256, 0, stream>>>(hin, srcp, dstp, pseudo, acc, E, nlo, nhi);
        dim3 nb((nhi - nlo + 63) / 64, (O + TO - 1) / TO);
        contract_kernel<I, O, TO><<<nb, 256, 0, stream>>>(acc, hin, W, root, bias, deg, hout, nlo, nhi);
    }
}

extern "C" void kernel_launch(void* const* d_in, const int* in_sizes, int n_in,
                              void* d_out, int out_size, void* d_ws, size_t ws_size,
                              hipStream_t stream) {
    const float* x      = (const float*)d_in[0];
    const int*   ei     = (const int*)  d_in[1];
    const float* pseudo = (const float*)d_in[2];
    const int*   batch  = (const int*)  d_in[3];
    const float* W1 = (const float*)d_in[4];
    const float* r1 = (const float*)d_in[5];
    const float* b1 = (const float*)d_in[6];
    const float* W2 = (const float*)d_in[7];
    const float* r2 = (const float*)d_in[8];
    const float* b2 = (const float*)d_in[9];
    const float* W3 = (const float*)d_in[10];
    const float* r3 = (const float*)d_in[11];
    const float* b3 = (const float*)d_in[12];
    const float* fcw = (const float*)d_in[13];
    const float* fcb = (const float*)d_in[14];

    int N = in_sizes[0] / 8;
    int E = in_sizes[1] / 2;
    const int* srcp = ei;
    const int* dstp = ei + E;

    // workspace carve
    char* p = (char*)d_ws;
    float* h1   = (float*)p; p += (size_t)N * 32 * 4;
    float* h2   = (float*)p; p += (size_t)N * 64 * 4;
    float* h3   = (float*)p; p += (size_t)N * 124 * 4;
    float* deg  = (float*)p; p += (size_t)N * 4;
    float* gbuf = (float*)p; p += 64 * 124 * 4;
    float* cnt  = (float*)p; p += 256;
    float* acc  = (float*)p;
    size_t used = (size_t)(p - (char*)d_ws);
    size_t avail = (ws_size > used) ? (ws_size - used) : 0;

    // zero deg + g + cnt in one shot (contiguous)
    hipMemsetAsync(deg, 0, (size_t)N * 4 + 64 * 124 * 4 + 256, stream);
    deg_count_kernel<<<(E + 255) / 256, 256, 0, stream>>>(dstp, deg, E);

    run_layer<8, 32, 32>(x,  W1, r1, b1, h1, acc, deg, srcp, dstp, pseudo, N, E, avail, stream);
    run_layer<32, 64, 64>(h1, W2, r2, b2, h2, acc, deg, srcp, dstp, pseudo, N, E, avail, stream);
    run_layer<64, 124, 64>(h2, W3, r3, b3, h3, acc, deg, srcp, dstp, pseudo, N, E, avail, stream);

    int tot = N * 124;
    graph_sum_kernel<<<(tot + 255) / 256, 256, 0, stream>>>(h3, batch, gbuf, cnt, N);
    head_kernel<<<64, 64, 0, stream>>>(gbuf, cnt, fcw, fcb, (float*)d_out);
}

// Round 3
// 1601.653 us; speedup vs baseline: 1.3424x; 1.1233x over previous
//
#include <hip/hip_runtime.h>
#include <cstdint>
#include <cstddef>

#define KKSLOTS 25

// ---------------------------------------------------------------------------
// degree count (incoming edges per node)
// ---------------------------------------------------------------------------
__global__ void deg_count_kernel(const int* __restrict__ dst, float* __restrict__ deg, int E) {
    int e = blockIdx.x * blockDim.x + threadIdx.x;
    if (e < E) atomicAdd(&deg[dst[e]], 1.0f);
}

// ---------------------------------------------------------------------------
// scatter edge messages in INPUT space: acc[dst, k, i] += w_c * x[src, i]
// one thread per (edge, i); 4 spline corners per thread.
// ---------------------------------------------------------------------------
template<int I>
__global__ void scatter_kernel(const float* __restrict__ x,
                               const int* __restrict__ src,
                               const int* __restrict__ dst,
                               const float* __restrict__ pseudo,
                               float* __restrict__ acc,
                               int E, int nlo, int nhi) {
    long long tid = (long long)blockIdx.x * blockDim.x + threadIdx.x;
    int e = (int)(tid / I);
    int i = (int)(tid % I);
    if (e >= E) return;
    int d = dst[e];
    if (d < nlo || d >= nhi) return;
    int s = src[e];
    float xv = x[(size_t)s * I + i];
    float v0 = pseudo[2 * e + 0] * 4.0f;   // (K-1) = 4
    float v1 = pseudo[2 * e + 1] * 4.0f;
    float fl0 = floorf(v0), fl1 = floorf(v1);
    float f0 = v0 - fl0, f1 = v1 - fl1;
    int b0 = (int)fl0, b1 = (int)fl1;
    float* base = acc + (size_t)(d - nlo) * (KKSLOTS * I) + i;
    #pragma unroll
    for (int s0 = 0; s0 < 2; ++s0) {
        float w0 = s0 ? f0 : (1.0f - f0);
        int i0 = min(max(b0 + s0, 0), 4);
        #pragma unroll
        for (int s1 = 0; s1 < 2; ++s1) {
            float w1 = s1 ? f1 : (1.0f - f1);
            int i1 = min(max(b1 + s1, 0), 4);
            atomicAdd(base + (size_t)(i0 * 5 + i1) * I, w0 * w1 * xv);
        }
    }
}

// ---------------------------------------------------------------------------
// dense contraction, register-blocked GEMM:
// hout[n,o] = elu( (sum_k acc[n,k]*W[k,o]) / deg[n] + sum_i hin[n,i]*root[i,o] + bias[o] )
// ---------------------------------------------------------------------------
template<int I, int O, int TO>
__global__ __launch_bounds__(256) void contract_kernel(
        const float* __restrict__ acc, const float* __restrict__ hin,
        const float* __restrict__ W, const float* __restrict__ root,
        const float* __restrict__ bias, const float* __restrict__ deg,
        float* __restrict__ hout, int nlo, int nhi) {
    constexpr int K   = KKSLOTS * I;
    constexpr int KCH = 64;
    constexpr int TN  = 64;
    constexpr int OG  = TO / 4;        // threads along o
    constexpr int NG  = 256 / OG;      // threads along n
    constexpr int NPT = TN / NG;       // node rows per thread
    __shared__ float a_tile[TN][KCH + 4];
    __shared__ float w_tile[KCH][TO];

    int tid = threadIdx.x;
    int n0 = nlo + blockIdx.x * TN;
    int otile = blockIdx.y * TO;
    int og = tid % OG;
    int ng = tid / OG;
    int obase = otile + og * 4;

    float c[NPT][4];
    #pragma unroll
    for (int j = 0; j < NPT; ++j)
        #pragma unroll
        for (int p = 0; p < 4; ++p) c[j][p] = 0.0f;

    for (int k0 = 0; k0 < K; k0 += KCH) {
        int kk = tid & 63;
        int rbase = (tid >> 6) * (TN / 4);
        int gk = k0 + kk;
        #pragma unroll
        for (int j2 = 0; j2 < TN / 4; ++j2) {
            int nn = rbase + j2;
            int n = n0 + nn;
            float v = 0.0f;
            if (n < nhi && gk < K) v = acc[(size_t)(n - nlo) * K + gk];
            a_tile[nn][kk] = v;
        }
        for (int t = tid; t < KCH * TO; t += 256) {
            int kq = t / TO, oq = t - kq * TO;
            int gkw = k0 + kq;
            int oo = otile + oq;
            w_tile[kq][oq] = (gkw < K && oo < O) ? W[(size_t)gkw * O + oo] : 0.0f;
        }
        __syncthreads();
        #pragma unroll 4
        for (int kk2 = 0; kk2 < KCH; kk2 += 4) {
            float4 wv0 = *(const float4*)&w_tile[kk2 + 0][og * 4];
            float4 wv1 = *(const float4*)&w_tile[kk2 + 1][og * 4];
            float4 wv2 = *(const float4*)&w_tile[kk2 + 2][og * 4];
            float4 wv3 = *(const float4*)&w_tile[kk2 + 3][og * 4];
            #pragma unroll
            for (int j = 0; j < NPT; ++j) {
                float4 av = *(const float4*)&a_tile[ng * NPT + j][kk2];
                c[j][0] = fmaf(av.x, wv0.x, c[j][0]); c[j][1] = fmaf(av.x, wv0.y, c[j][1]);
                c[j][2] = fmaf(av.x, wv0.z, c[j][2]); c[j][3] = fmaf(av.x, wv0.w, c[j][3]);
                c[j][0] = fmaf(av.y, wv1.x, c[j][0]); c[j][1] = fmaf(av.y, wv1.y, c[j][1]);
                c[j][2] = fmaf(av.y, wv1.z, c[j][2]); c[j][3] = fmaf(av.y, wv1.w, c[j][3]);
                c[j][0] = fmaf(av.z, wv2.x, c[j][0]); c[j][1] = fmaf(av.z, wv2.y, c[j][1]);
                c[j][2] = fmaf(av.z, wv2.z, c[j][2]); c[j][3] = fmaf(av.z, wv2.w, c[j][3]);
                c[j][0] = fmaf(av.w, wv3.x, c[j][0]); c[j][1] = fmaf(av.w, wv3.y, c[j][1]);
                c[j][2] = fmaf(av.w, wv3.z, c[j][2]); c[j][3] = fmaf(av.w, wv3.w, c[j][3]);
            }
        }
        __syncthreads();
    }

    if (obase >= O) return;
    bool full4 = (obase + 3 < O);
    #pragma unroll
    for (int j = 0; j < NPT; ++j) {
        int n = n0 + ng * NPT + j;
        if (n >= nhi) continue;
        float dinv = 1.0f / fmaxf(deg[n], 1.0f);
        float r[4] = {0.0f, 0.0f, 0.0f, 0.0f};
        if (full4) {
            for (int i = 0; i < I; ++i) {
                float hv = hin[(size_t)n * I + i];
                float4 rt = *(const float4*)&root[(size_t)i * O + obase];
                r[0] = fmaf(hv, rt.x, r[0]); r[1] = fmaf(hv, rt.y, r[1]);
                r[2] = fmaf(hv, rt.z, r[2]); r[3] = fmaf(hv, rt.w, r[3]);
            }
        } else {
            for (int i = 0; i < I; ++i) {
                float hv = hin[(size_t)n * I + i];
                #pragma unroll
                for (int p = 0; p < 4; ++p)
                    if (obase + p < O) r[p] = fmaf(hv, root[(size_t)i * O + obase + p], r[p]);
            }
        }
        #pragma unroll
        for (int p = 0; p < 4; ++p) {
            int oo = obase + p;
            if (oo >= O) continue;
            float v = fmaf(c[j][p], dinv, r[p] + bias[oo]);
            hout[(size_t)n * O + oo] = (v > 0.0f) ? v : expm1f(v);
        }
    }
}

// ---------------------------------------------------------------------------
// segmented graph sum (batch is SORTED): block = chunk of CH nodes, thread =
// channel. Register accumulation within a batch segment; atomic only on
// segment change (~1.3 segments/chunk -> ~40K atomics total vs 3.7M flat).
// ---------------------------------------------------------------------------
#define GS_CH 128
__global__ __launch_bounds__(128) void graph_reduce_kernel(
        const float* __restrict__ h3, const int* __restrict__ batch,
        float* __restrict__ g, int N) {
    int o = threadIdx.x;
    if (o >= 124) return;
    int n0 = blockIdx.x * GS_CH;
    int n1 = min(n0 + GS_CH, N);
    float local = 0.0f;
    int cur_b = batch[n0];
    for (int n = n0; n < n1; ++n) {
        int b = batch[n];
        if (b != cur_b) {
            atomicAdd(&g[cur_b * 124 + o], local);
            local = 0.0f;
            cur_b = b;
        }
        local += h3[(size_t)n * 124 + o];
    }
    atomicAdd(&g[cur_b * 124 + o], local);
}

// per-block LDS histogram of batch ids -> few global atomics
__global__ __launch_bounds__(256) void batch_count_kernel(
        const int* __restrict__ batch, float* __restrict__ cnt, int N) {
    __shared__ int hist[64];
    int tid = threadIdx.x;
    if (tid < 64) hist[tid] = 0;
    __syncthreads();
    int n = blockIdx.x * blockDim.x + tid;
    if (n < N) atomicAdd(&hist[batch[n]], 1);
    __syncthreads();
    if (tid < 64 && hist[tid] > 0) atomicAdd(&cnt[tid], (float)hist[tid]);
}

// ---------------------------------------------------------------------------
// head: logits = (g/cnt) @ fc_w + fc_b ; log_softmax
// ---------------------------------------------------------------------------
__global__ void head_kernel(const float* __restrict__ g, const float* __restrict__ cnt,
                            const float* __restrict__ fcw, const float* __restrict__ fcb,
                            float* __restrict__ out) {
    __shared__ float logits[32];
    __shared__ float red[2];
    int b = blockIdx.x;
    int o = threadIdx.x;
    float c = fmaxf(cnt[b], 1.0f);
    if (o < 30) {
        float a = fcb[o];
        for (int i = 0; i < 124; ++i)
            a = fmaf(g[b * 124 + i] / c, fcw[i * 30 + o], a);
        logits[o] = a;
    }
    __syncthreads();
    if (o == 0) {
        float m = -1e30f;
        for (int j = 0; j < 30; ++j) m = fmaxf(m, logits[j]);
        float s = 0.0f;
        for (int j = 0; j < 30; ++j) s += expf(logits[j] - m);
        red[0] = m;
        red[1] = logf(s);
    }
    __syncthreads();
    if (o < 30) out[b * 30 + o] = logits[o] - red[0] - red[1];
}

// ---------------------------------------------------------------------------
// per-layer driver (node-chunked so acc fits whatever ws_size allows)
// ---------------------------------------------------------------------------
template<int I, int O, int TO>
static void run_layer(const float* hin, const float* W, const float* root, const float* bias,
                      float* hout, float* acc, const float* deg,
                      const int* srcp, const int* dstp, const float* pseudo,
                      int N, int E, size_t avail, hipStream_t stream) {
    size_t perNode = (size_t)KKSLOTS * I * 4;
    size_t maxNodesS = avail / perNode;
    int maxNodes = (maxNodesS > (size_t)N) ? N : (int)maxNodesS;
    if (maxNodes < 1) maxNodes = 1;
    for (int nlo = 0; nlo < N; nlo += maxNodes) {
        int nhi = nlo + maxNodes;
        if (nhi > N) nhi = N;
        hipMemsetAsync(acc, 0, (size_t)(nhi - nlo) * perNode, stream);
        long long threads = (long long)E * I;
        int blocks = (int)((threads + 255) / 256);
        scatter_kernel<I><<<blocks, 256, 0, stream>>>(hin, srcp, dstp, pseudo, acc, E, nlo, nhi);
        dim3 nb((nhi - nlo + 63) / 64, (O + TO - 1) / TO);
        contract_kernel<I, O, TO><<<nb, 256, 0, stream>>>(acc, hin, W, root, bias, deg, hout, nlo, nhi);
    }
}

extern "C" void kernel_launch(void* const* d_in, const int* in_sizes, int n_in,
                              void* d_out, int out_size, void* d_ws, size_t ws_size,
                              hipStream_t stream) {
    const float* x      = (const float*)d_in[0];
    const int*   ei     = (const int*)  d_in[1];
    const float* pseudo = (const float*)d_in[2];
    const int*   batch  = (const int*)  d_in[3];
    const float* W1 = (const float*)d_in[4];
    const float* r1 = (const float*)d_in[5];
    const float* b1 = (const float*)d_in[6];
    const float* W2 = (const float*)d_in[7];
    const float* r2 = (const float*)d_in[8];
    const float* b2 = (const float*)d_in[9];
    const float* W3 = (const float*)d_in[10];
    const float* r3 = (const float*)d_in[11];
    const float* b3 = (const float*)d_in[12];
    const float* fcw = (const float*)d_in[13];
    const float* fcb = (const float*)d_in[14];

    int N = in_sizes[0] / 8;
    int E = in_sizes[1] / 2;
    const int* srcp = ei;
    const int* dstp = ei + E;

    // workspace carve
    char* p = (char*)d_ws;
    float* h1   = (float*)p; p += (size_t)N * 32 * 4;
    float* h2   = (float*)p; p += (size_t)N * 64 * 4;
    float* h3   = (float*)p; p += (size_t)N * 124 * 4;
    float* deg  = (float*)p; p += (size_t)N * 4;
    float* gbuf = (float*)p; p += 64 * 124 * 4;
    float* cnt  = (float*)p; p += 256;
    float* acc  = (float*)p;
    size_t used = (size_t)(p - (char*)d_ws);
    size_t avail = (ws_size > used) ? (ws_size - used) : 0;

    // zero deg + g + cnt in one shot (contiguous)
    hipMemsetAsync(deg, 0, (size_t)N * 4 + 64 * 124 * 4 + 256, stream);
    deg_count_kernel<<<(E + 255) / 256, 256, 0, stream>>>(dstp, deg, E);

    run_layer<8, 32, 32>(x,  W1, r1, b1, h1, acc, deg, srcp, dstp, pseudo, N, E, avail, stream);
    run_layer<32, 64, 64>(h1, W2, r2, b2, h2, acc, deg, srcp, dstp, pseudo, N, E, avail, stream);
    run_layer<64, 124, 64>(h2, W3, r3, b3, h3, acc, deg, srcp, dstp, pseudo, N, E, avail, stream);

    graph_reduce_kernel<<<(N + GS_CH - 1) / GS_CH, 128, 0, stream>>>(h3, batch, gbuf, N);
    batch_count_kernel<<<(N + 255) / 256, 256, 0, stream>>>(batch, cnt, N);
    head_kernel<<<64, 64, 0, stream>>>(gbuf, cnt, fcw, fcb, (float*)d_out);
}